// Round 5
// baseline (94.931 us; speedup 1.0000x reference)
//
#include <hip/hip_runtime.h>
#include <hip/hip_bf16.h>

// MMD loss: source/target 4096x256 fp32, output = scalar fp32.
// N = 8192 rows, D = 256.
//
// Key idea this revision: the Gram pass needs A- and B-fragments with the
// SAME MFMA lane layout (lane = 16*kslot + row). So k_prep stores the bf16
// matrix in MFMA-native tiled layout G2, where every fragment is one
// contiguous 1 KB block:
//   G2[((tile*8 + kc)*4 + fr)*512 + lane*8 + e],
//   tile=r>>6, fr=(r>>4)&3, rl=r&15, lane=16*kl+rl, k = kl*8+e (kc chunk of 32)
// k_mmd then runs ONE WAVE PER 64x64 PAIR-TILE: fragments loaded directly
// from L2 via coalesced 1KB loads. No LDS, no barriers, no staging; waves
// drift freely so MFMA/VMEM/epilogue-VALU from different waves co-schedule.
//
// ws: doubles d[0..255]=colsum, d[256]=neg_gamma2, d[257..288]=acc slots;
//     float sq[8192] at byte 4096; bf16 G2[8192*256] at byte 36864.
#define WS_D_COLSUM 0
#define WS_D_NEGG   256
#define WS_D_ACC    257
#define WS_ACC_SLOTS 32
#define WS_SQ_OFF   4096
#define WS_G_OFF    36864

#define NROW 8192
#define HALF 4096
#define DIM  256
#define TT   64                    // pair-tile size (per wave)
#define NT   128                   // 8192/64 row-tiles
#define NPAIR (NT * (NT + 1) / 2)  // 8256 upper-tri pairs
#define NBLK  (NPAIR / 4)          // 2064 blocks x 4 waves
#define TILE_US (8 * 4 * 512)      // ushorts per row-tile in G2 (32 KB)

typedef short  short8 __attribute__((ext_vector_type(8)));
typedef float  f32x4  __attribute__((ext_vector_type(4)));
typedef unsigned short us4 __attribute__((ext_vector_type(4)));

static __device__ __forceinline__ unsigned short f2bfbits(float f) {
    __hip_bfloat16 h = __float2bfloat16(f);   // RNE
    return *reinterpret_cast<unsigned short*>(&h);
}
static __device__ __forceinline__ float bfbits2f(unsigned short u) {
    return __uint_as_float(((unsigned int)u) << 16);
}

// ---------- kernel A: cvt to G2 (MFMA-tiled) + row-sq + colsum ----------
// 128 blocks x 256 threads; block = row-tile pair? No: block handles 64 rows
// (= exactly one G2 tile); wave w handles rows r0 + w + 4i.
__global__ __launch_bounds__(256) void k_prep(const float* __restrict__ src,
                                              const float* __restrict__ tgt,
                                              unsigned short* __restrict__ G2,
                                              float* __restrict__ sq,
                                              double* __restrict__ colsum) {
    __shared__ float cs_lds[4 * 256];
    int t = threadIdx.x, wid = t >> 6, lane = t & 63;
    int r0 = blockIdx.x * 64;
    int c4 = lane * 4;
    // G2 lane-invariant part: kc = lane>>3, kl = (lane>>1)&3, e4 = (lane&1)*4
    int lanepart = (lane >> 3) * 2048 + ((lane >> 1) & 3) * 128 + (lane & 1) * 4;
    size_t tilebase = (size_t)blockIdx.x * TILE_US;

    float cs0 = 0.f, cs1 = 0.f, cs2 = 0.f, cs3 = 0.f;
    for (int i = 0; i < 16; ++i) {
        int row = r0 + wid + i * 4;
        const float* base = (row < HALF) ? (src + (size_t)row * DIM)
                                         : (tgt + (size_t)(row - HALF) * DIM);
        float4 v = *(const float4*)(base + c4);
        unsigned short u0 = f2bfbits(v.x), u1 = f2bfbits(v.y),
                       u2 = f2bfbits(v.z), u3 = f2bfbits(v.w);
        us4 uu = {u0, u1, u2, u3};
        int fr = (row >> 4) & 3, rl = row & 15;
        *(us4*)(G2 + tilebase + fr * 512 + rl * 8 + lanepart) = uu;
        float r0f = bfbits2f(u0), r1f = bfbits2f(u1),
              r2f = bfbits2f(u2), r3f = bfbits2f(u3);
        cs0 += r0f; cs1 += r1f; cs2 += r2f; cs3 += r3f;
        float s = r0f * r0f + r1f * r1f + r2f * r2f + r3f * r3f;
        #pragma unroll
        for (int off = 32; off; off >>= 1) s += __shfl_down(s, off);
        if (lane == 0) sq[row] = s;
    }
    cs_lds[wid * 256 + c4 + 0] = cs0;
    cs_lds[wid * 256 + c4 + 1] = cs1;
    cs_lds[wid * 256 + c4 + 2] = cs2;
    cs_lds[wid * 256 + c4 + 3] = cs3;
    __syncthreads();
    double s = (double)cs_lds[t] + (double)cs_lds[256 + t] +
               (double)cs_lds[512 + t] + (double)cs_lds[768 + t];
    atomicAdd(&colsum[t], s);  // 128-deep per address
}

// ---------- kernel B: bandwidth -> neg_gamma2 = -log2(e)/(16*bw) ----------
__global__ __launch_bounds__(256) void k_bw(const float* __restrict__ sq,
                                            double* __restrict__ wsd) {
    __shared__ double red[256];
    __shared__ double red2[256];
    int t = threadIdx.x;
    double s = 0.0;
    for (int i = t; i < NROW; i += 256) s += (double)sq[i];
    double c = wsd[WS_D_COLSUM + t];
    red[t]  = s;
    red2[t] = c * c;
    __syncthreads();
    for (int off = 128; off; off >>= 1) {
        if (t < off) { red[t] += red[t + off]; red2[t] += red2[t + off]; }
        __syncthreads();
    }
    if (t == 0) {
        const double N = (double)NROW;
        double sum_l2 = 2.0 * N * red[0] - 2.0 * red2[0];
        double bw = sum_l2 / (N * N - N);
        bw = bw / 4.0;  // KERNEL_MUL ** (KERNEL_NUM//2) = 2^2
        wsd[WS_D_NEGG] = -1.4426950408889634 / (16.0 * bw);  // exp2 scaling
    }
}

// ---------- kernel D: one wave per 64x64 pair-tile, no LDS, no barriers ----
__global__ __launch_bounds__(256, 3) void k_mmd(const unsigned short* __restrict__ G2,
                                                const float* __restrict__ sq,
                                                const double* __restrict__ wsd,
                                                double* __restrict__ acc_slots) {
    // XCD-chunked bijective swizzle (NBLK = 2064 = 8*258)
    int bid = blockIdx.x;
    int swz = (bid & 7) * (NBLK / 8) + (bid >> 3);

    int wid = threadIdx.x >> 6, lane = threadIdx.x & 63;
    int p = swz * 4 + wid;            // this wave's pair index
    int ti = 0, rem = p;              // triangular decode (wave-uniform)
    while (rem >= NT - ti) { rem -= NT - ti; ++ti; }
    int tj = ti + rem;

    const unsigned short* Ab = G2 + (size_t)ti * TILE_US;
    const unsigned short* Bb = G2 + (size_t)tj * TILE_US;
    int lo = lane * 8;                // ushort offset inside a 1KB frag block

    const f32x4 zero4 = {0.f, 0.f, 0.f, 0.f};
    f32x4 acc[4][4];
    #pragma unroll
    for (int i = 0; i < 4; ++i)
        #pragma unroll
        for (int j = 0; j < 4; ++j) acc[i][j] = zero4;

    short8 a0[4], b0[4], a1[4], b1[4];

    #define LOADSET(A, B, kc)                                            \
        do {                                                             \
            _Pragma("unroll")                                            \
            for (int f = 0; f < 4; ++f) {                                \
                A[f] = *(const short8*)&Ab[((kc) * 4 + f) * 512 + lo];   \
                B[f] = *(const short8*)&Bb[((kc) * 4 + f) * 512 + lo];   \
            }                                                            \
        } while (0)
    #define MFMASET(A, B)                                                \
        do {                                                             \
            _Pragma("unroll")                                            \
            for (int i = 0; i < 4; ++i)                                  \
                _Pragma("unroll")                                        \
                for (int j = 0; j < 4; ++j)                              \
                    acc[i][j] = __builtin_amdgcn_mfma_f32_16x16x32_bf16( \
                        A[i], B[j], acc[i][j], 0, 0, 0);                 \
        } while (0)

    LOADSET(a0, b0, 0);
    #pragma unroll
    for (int k2 = 0; k2 < 4; ++k2) {
        LOADSET(a1, b1, 2 * k2 + 1);
        MFMASET(a0, b0);
        if (k2 < 3) LOADSET(a0, b0, 2 * k2 + 2);
        MFMASET(a1, b1);
    }
    #undef LOADSET
    #undef MFMASET

    // epilogue: l2 -> 5-kernel sum via exp2-squaring chain
    // C/D layout (m89): col = lane&15, row = (lane>>4)*4 + reg
    int gi0 = ti * TT;
    int gj0 = tj * TT;
    float ng2 = (float)wsd[WS_D_NEGG];
    int rl16 = lane & 15, rgrp = lane >> 4;

    float sqb4[4];
    #pragma unroll
    for (int j = 0; j < 4; ++j) sqb4[j] = sq[gj0 + j * 16 + rl16];

    float tsum = 0.f;
    #pragma unroll
    for (int i = 0; i < 4; ++i) {
        float sqa4[4];
        #pragma unroll
        for (int rr = 0; rr < 4; ++rr) sqa4[rr] = sq[gi0 + i * 16 + rgrp * 4 + rr];
        #pragma unroll
        for (int j = 0; j < 4; ++j) {
            #pragma unroll
            for (int rr = 0; rr < 4; ++rr) {
                float l2 = fmaxf(sqa4[rr] + sqb4[j] - 2.0f * acc[i][j][rr], 0.f);
                float e   = exp2f(l2 * ng2);   // exp(-l2/(16 bw)) == kernel i=4
                float e2  = e * e;             // i=3
                float e4  = e2 * e2;           // i=2
                float e8  = e4 * e4;           // i=1
                float e16 = e8 * e8;           // i=0
                tsum += e + e2 + e4 + e8 + e16;
            }
        }
    }

    float w = ((ti < NT / 2) == (tj < NT / 2)) ? 1.f : -1.f;
    if (ti != tj) w *= 2.f;   // off-diagonal tiles count twice (symmetry)
    double dsum = (double)tsum * (double)w;

    #pragma unroll
    for (int off = 32; off; off >>= 1) dsum += __shfl_down(dsum, off);
    if (lane == 0)
        atomicAdd(&acc_slots[p & (WS_ACC_SLOTS - 1)], dsum);
}

// ---------- kernel E: finalize ----------
__global__ void k_final(const double* __restrict__ wsd, float* __restrict__ out) {
    double s = 0.0;
    for (int i = 0; i < WS_ACC_SLOTS; ++i) s += wsd[WS_D_ACC + i];
    out[0] = (float)(s / ((double)HALF * (double)HALF));
}

extern "C" void kernel_launch(void* const* d_in, const int* in_sizes, int n_in,
                              void* d_out, int out_size, void* d_ws, size_t ws_size,
                              hipStream_t stream) {
    const float* src = (const float*)d_in[0];
    const float* tgt = (const float*)d_in[1];
    float* out = (float*)d_out;

    double* wsd        = (double*)d_ws;
    float* sq          = (float*)((char*)d_ws + WS_SQ_OFF);
    unsigned short* G2 = (unsigned short*)((char*)d_ws + WS_G_OFF);

    // zero colsum + negg + acc slots every launch
    hipMemsetAsync(d_ws, 0, 4096, stream);

    k_prep<<<NROW / 64, 256, 0, stream>>>(src, tgt, G2, sq, &wsd[WS_D_COLSUM]);
    k_bw<<<1, 256, 0, stream>>>(sq, wsd);

    k_mmd<<<NBLK, 256, 0, stream>>>(G2, sq, wsd, &wsd[WS_D_ACC]);

    k_final<<<1, 1, 0, stream>>>(wsd, out);
}